// Round 4
// baseline (469.745 us; speedup 1.0000x reference)
//
#include <hip/hip_runtime.h>
#include <hip/hip_bf16.h>

// B=4, S=2048, F=512, E=512, H=8, DH=64
// Pipeline: f32->f16 cast, LDS-staged fused QKV MFMA GEMM (m97 recipe),
// flash attention with swapped-operand QK^T (register-local softmax + P->PV).
// Workspace:
//   xh  [8192][512] f16        @ 0        (8 MB)
//   wT  [3][512][512] f16      @ 8388608  (1.5 MB)   wT[z][n][k] = W_z[k][n]
//   Qh  [32][2048][64] f16     @ 9961472  (8 MB)     (no etype; added in attn)
//   Kh  [32][2048][64] f16     @ 18350080 (8 MB)
//   Vt  [32][64][2048] f16     @ 26738688 (8 MB)     V transposed per head

typedef _Float16 f16x4 __attribute__((ext_vector_type(4)));
typedef _Float16 f16x8 __attribute__((ext_vector_type(8)));
typedef float f32x4 __attribute__((ext_vector_type(4)));

#define MFMA16(a, b, c) __builtin_amdgcn_mfma_f32_16x16x16f16((a), (b), (c), 0, 0, 0)
#define MFMA32(a, b, c) __builtin_amdgcn_mfma_f32_16x16x32_f16((a), (b), (c), 0, 0, 0)

constexpr int Bn = 4, Sn = 2048, Fn = 512, En = 512, Hn = 8, DHn = 64;

__global__ void cvt_f32_to_f16(const float* __restrict__ in, _Float16* __restrict__ out, int n4) {
    int i = blockIdx.x * blockDim.x + threadIdx.x;
    int stride = gridDim.x * blockDim.x;
    for (; i < n4; i += stride) {
        float4 v = reinterpret_cast<const float4*>(in)[i];
        f16x4 o = { (_Float16)v.x, (_Float16)v.y, (_Float16)v.z, (_Float16)v.w };
        reinterpret_cast<f16x4*>(out)[i] = o;
    }
}

// wT[z][n][k] = W_z[k][n]
__global__ void cvt_wT(const float* __restrict__ Wq, const float* __restrict__ Wk,
                       const float* __restrict__ Wv, _Float16* __restrict__ out) {
    const int z = blockIdx.z;
    const float* W = (z == 0) ? Wq : ((z == 1) ? Wk : Wv);
    _Float16* o = out + (size_t)z * Fn * En;
    __shared__ float tile[16][17];
    int n = blockIdx.x * 16 + threadIdx.x;
    int k = blockIdx.y * 16 + threadIdx.y;
    tile[threadIdx.y][threadIdx.x] = W[k * En + n];
    __syncthreads();
    int n2 = blockIdx.x * 16 + threadIdx.y;
    int k2 = blockIdx.y * 16 + threadIdx.x;
    o[(size_t)n2 * Fn + k2] = (_Float16)tile[threadIdx.x][threadIdx.y];
}

// Fused QKV GEMM, m97-style: 128x128 tile, BK=64, global_load_lds(16B) staging
// with XOR swizzle. 4 waves, each a 64x64 quadrant, K=32 f16 MFMA. grid (64,4,3).
__global__ __launch_bounds__(256) void qkv_gemm(
    const _Float16* __restrict__ xh, const _Float16* __restrict__ wT,
    const float* __restrict__ bq, const float* __restrict__ bk, const float* __restrict__ bv,
    _Float16* __restrict__ Qh, _Float16* __restrict__ Kh, _Float16* __restrict__ Vt) {
    const int z = blockIdx.z;
    const _Float16* Wz = wT + (size_t)z * Fn * En;
    const float* bias = (z == 0) ? bq : ((z == 1) ? bk : bv);

    const int tid = threadIdx.x;
    const int wave = tid >> 6, lane = tid & 63;
    const int lr = lane & 15, hi = lane >> 4;
    const int wr = wave >> 1, wc = wave & 1;
    const int m0 = blockIdx.x * 128;
    const int n0 = blockIdx.y * 128;

    __shared__ __align__(16) char smem[32768];
    char* As = smem;
    char* Bs = smem + 16384;

    f32x4 acc[4][4] = {};

    const int inrow = (tid & 7) * 16;
    const int rowb = tid >> 3;

    const char* xg = (const char*)xh;
    const char* wg = (const char*)Wz;

    for (int t = 0; t < 8; ++t) {
        const int k0b = t * 128;
        __syncthreads();
#pragma unroll
        for (int it = 0; it < 4; ++it) {
            const int row = rowb + it * 32;
            const int srccol = inrow ^ ((row & 7) << 4);
            const char* ga = xg + (size_t)(m0 + row) * 1024 + k0b + srccol;
            const char* gb = wg + (size_t)(n0 + row) * 1024 + k0b + srccol;
            const int ldso = (it * 256 + tid) * 16;
            __builtin_amdgcn_global_load_lds((const __attribute__((address_space(1))) void*)ga,
                                             (__attribute__((address_space(3))) void*)(As + ldso), 16, 0, 0);
            __builtin_amdgcn_global_load_lds((const __attribute__((address_space(1))) void*)gb,
                                             (__attribute__((address_space(3))) void*)(Bs + ldso), 16, 0, 0);
        }
        asm volatile("s_waitcnt vmcnt(0)" ::: "memory");
        __syncthreads();
#pragma unroll
        for (int ks = 0; ks < 2; ++ks) {
            f16x8 af[4], bf[4];
            const int kb = ks * 64 + hi * 16;
#pragma unroll
            for (int mt = 0; mt < 4; ++mt) {
                const int row = wr * 64 + mt * 16 + lr;
                af[mt] = *reinterpret_cast<const f16x8*>(As + row * 128 + (kb ^ ((row & 7) << 4)));
            }
#pragma unroll
            for (int nt = 0; nt < 4; ++nt) {
                const int row = wc * 64 + nt * 16 + lr;
                bf[nt] = *reinterpret_cast<const f16x8*>(Bs + row * 128 + (kb ^ ((row & 7) << 4)));
            }
#pragma unroll
            for (int mt = 0; mt < 4; ++mt)
#pragma unroll
                for (int nt = 0; nt < 4; ++nt)
                    acc[mt][nt] = MFMA32(af[mt], bf[nt], acc[mt][nt]);
        }
    }

#pragma unroll
    for (int mt = 0; mt < 4; ++mt) {
        const int gr0 = m0 + wr * 64 + mt * 16 + hi * 4;
#pragma unroll
        for (int nt = 0; nt < 4; ++nt) {
            const int col = n0 + wc * 64 + nt * 16 + lr;
            const int hh = col >> 6, dd = col & 63;
            const float bz = bias[col];
            if (z == 2) {
                f16x4 vv;
#pragma unroll
                for (int r = 0; r < 4; ++r) vv[r] = (_Float16)(acc[mt][nt][r] + bz);
                const int bb = gr0 >> 11, ss = gr0 & 2047;
                *reinterpret_cast<f16x4*>(Vt + ((size_t)(bb * Hn + hh) * DHn + dd) * Sn + ss) = vv;
            } else {
                _Float16* dst = (z == 0) ? Qh : Kh;
#pragma unroll
                for (int r = 0; r < 4; ++r) {
                    const int row = gr0 + r;
                    const int bb = row >> 11, ss = row & 2047;
                    dst[((size_t)(bb * Hn + hh) * Sn + ss) * DHn + dd] = (_Float16)(acc[mt][nt][r] + bz);
                }
            }
        }
    }
}

// Flash attention, swapped-operand, high-occupancy form.
// grid 1024 1D: bid = qb*32 + bh  (bid%8 == bh%8 -> one head's blocks share an XCD L2).
// 4 waves/block, 16 q-rows/wave. Softmax state fully lane-local (col = l&15 = q-row);
// row-sum accumulated on the MFMA pipe via a ones-row (osum); defer-max (THR=8).
__global__ __launch_bounds__(256, 4) void attn(
    const _Float16* __restrict__ Qh, const _Float16* __restrict__ Kh,
    const _Float16* __restrict__ Vt, const int* __restrict__ mask,
    const float* __restrict__ etype, float* __restrict__ out) {
    const int bid = blockIdx.x;
    const int bh = bid & 31, qb = bid >> 5;
    const int b = bh >> 3, h = bh & 7;
    const int wave = threadIdx.x >> 6, lane = threadIdx.x & 63;
    const int lr = lane & 15, hi = lane >> 4;
    const int q0 = qb * 64 + wave * 16;

    const _Float16* Qb = Qh + (size_t)bh * Sn * DHn;
    const _Float16* Kb = Kh + (size_t)bh * Sn * DHn;
    const _Float16* Vb = Vt + (size_t)bh * Sn * DHn;  // [64][2048]
    const int* mb = mask + b * Sn;

    constexpr float CSC = 0.18033688011112042f;  // 0.125 * log2(e)
    constexpr int NT = Sn / 64;

    // Q fragment: col = l&15 = q-row, k = ks*32 + hi*8 + e. Add etype + prescale once.
    f16x8 qf[2];
#pragma unroll
    for (int ks = 0; ks < 2; ++ks) {
        const f16x8 qh = *reinterpret_cast<const f16x8*>(Qb + (q0 + lr) * DHn + ks * 32 + hi * 8);
        const float* ep = etype + ((size_t)(b * Sn) + q0 + lr) * En + h * DHn + ks * 32 + hi * 8;
        const f32x4 e0 = *reinterpret_cast<const f32x4*>(ep);
        const f32x4 e1 = *reinterpret_cast<const f32x4*>(ep + 4);
        f16x8 q;
#pragma unroll
        for (int j = 0; j < 4; ++j) q[j] = (_Float16)(((float)qh[j] + e0[j]) * CSC);
#pragma unroll
        for (int j = 0; j < 4; ++j) q[4 + j] = (_Float16)(((float)qh[4 + j] + e1[j]) * CSC);
        qf[ks] = q;
    }

    // K fragments: row = l&15 = key, k = ks*32 + hi*8 + e. Reloaded in place each tile.
    f16x8 kf[4][2];
#pragma unroll
    for (int kt = 0; kt < 4; ++kt)
#pragma unroll
        for (int ks = 0; ks < 2; ++ks)
            kf[kt][ks] = *reinterpret_cast<const f16x8*>(Kb + (kt * 16 + lr) * DHn + ks * 32 + hi * 8);

    f32x4 oaccT[4] = {};  // [dt]: row = d-local (hi*4+r), col = q-row (l&15)
    f32x4 osum = {};      // ones-row accumulator: every element = running sum for q-row l&15
    float mrun = -3e38f;

    const f16x4 onev = {(_Float16)1.f, (_Float16)1.f, (_Float16)1.f, (_Float16)1.f};

    for (int t = 0; t < NT; ++t) {
        const int key0 = t * 64;

        int4 km[4];
#pragma unroll
        for (int kt = 0; kt < 4; ++kt)
            km[kt] = *reinterpret_cast<const int4*>(mb + key0 + kt * 16 + hi * 4);

        // S^T = K·Q^T (pre-scaled): D row = key-local (hi*4+r), col = q-row (l&15)
        f32x4 scT[4] = {};
#pragma unroll
        for (int ks = 0; ks < 2; ++ks)
#pragma unroll
            for (int kt = 0; kt < 4; ++kt)
                scT[kt] = MFMA32(kf[kt][ks], qf[ks], scT[kt]);

        // reload K for next tile in place (latency hidden under softmax + PV)
        const int nk0 = (t + 1 < NT) ? key0 + 64 : 0;
#pragma unroll
        for (int kt = 0; kt < 4; ++kt)
#pragma unroll
            for (int ks = 0; ks < 2; ++ks)
                kf[kt][ks] = *reinterpret_cast<const f16x8*>(Kb + (nk0 + kt * 16 + lr) * DHn + ks * 32 + hi * 8);

        // V first half (A-operand of PV: row = l&15 = d, k = key (hi*4+e))
        f16x4 vf[4][4];
#pragma unroll
        for (int ks = 0; ks < 2; ++ks)
#pragma unroll
            for (int dt = 0; dt < 4; ++dt)
                vf[ks][dt] = *reinterpret_cast<const f16x4*>(Vb + (dt * 16 + lr) * Sn + key0 + ks * 16 + hi * 4);

        // key-mask -> -1e30 (exact for all-masked tiles -> uniform weights, matches ref)
        scT[0][0] = km[0].x ? scT[0][0] : -1e30f; scT[0][1] = km[0].y ? scT[0][1] : -1e30f;
        scT[0][2] = km[0].z ? scT[0][2] : -1e30f; scT[0][3] = km[0].w ? scT[0][3] : -1e30f;
        scT[1][0] = km[1].x ? scT[1][0] : -1e30f; scT[1][1] = km[1].y ? scT[1][1] : -1e30f;
        scT[1][2] = km[1].z ? scT[1][2] : -1e30f; scT[1][3] = km[1].w ? scT[1][3] : -1e30f;
        scT[2][0] = km[2].x ? scT[2][0] : -1e30f; scT[2][1] = km[2].y ? scT[2][1] : -1e30f;
        scT[2][2] = km[2].z ? scT[2][2] : -1e30f; scT[2][3] = km[2].w ? scT[2][3] : -1e30f;
        scT[3][0] = km[3].x ? scT[3][0] : -1e30f; scT[3][1] = km[3].y ? scT[3][1] : -1e30f;
        scT[3][2] = km[3].z ? scT[3][2] : -1e30f; scT[3][3] = km[3].w ? scT[3][3] : -1e30f;

        // row max: 16 lane-local + 2 shuffles
        float mx = -3e38f;
#pragma unroll
        for (int kt = 0; kt < 4; ++kt)
#pragma unroll
            for (int r = 0; r < 4; ++r) mx = fmaxf(mx, scT[kt][r]);
        mx = fmaxf(mx, __shfl_xor(mx, 16));
        mx = fmaxf(mx, __shfl_xor(mx, 32));

        // defer-max: only rescale when the max really grew (THR=8 -> P <= 256, fine in f16)
        if (!__all(mx <= mrun + 8.0f)) {
            const float mnew = fmaxf(mrun, mx);
            const float al = exp2f(mrun - mnew);
            mrun = mnew;
#pragma unroll
            for (int dt = 0; dt < 4; ++dt) oaccT[dt] *= al;
            osum *= al;
        }

        // P = exp2(S - m), pack to f16 (register-local: same (kt,r) index as PV's k-slot)
        f16x4 pa[4];
#pragma unroll
        for (int kt = 0; kt < 4; ++kt) {
            f16x4 p;
#pragma unroll
            for (int r = 0; r < 4; ++r) p[r] = (_Float16)exp2f(scT[kt][r] - mrun);
            pa[kt] = p;
        }

        // V second half
#pragma unroll
        for (int ks = 2; ks < 4; ++ks)
#pragma unroll
            for (int dt = 0; dt < 4; ++dt)
                vf[ks][dt] = *reinterpret_cast<const f16x4*>(Vb + (dt * 16 + lr) * Sn + key0 + ks * 16 + hi * 4);

        // O^T += V^T·P^T ; row-sum via ones-row on the MFMA pipe
#pragma unroll
        for (int ks = 0; ks < 4; ++ks) {
#pragma unroll
            for (int dt = 0; dt < 4; ++dt)
                oaccT[dt] = MFMA16(vf[ks][dt], pa[ks], oaccT[dt]);
            osum = MFMA16(onev, pa[ks], osum);
        }
    }

    // epilogue: query-mask zeroing + 1/sum
    const int srow = q0 + lr;
    const float inv = (mb[srow] != 0) ? 1.0f / osum[0] : 0.0f;
#pragma unroll
    for (int dt = 0; dt < 4; ++dt) {
        f32x4 o = oaccT[dt] * inv;
        *reinterpret_cast<f32x4*>(out + ((size_t)(b * Sn + srow)) * En + h * DHn + dt * 16 + hi * 4) = o;
    }
}

extern "C" void kernel_launch(void* const* d_in, const int* in_sizes, int n_in,
                              void* d_out, int out_size, void* d_ws, size_t ws_size,
                              hipStream_t stream) {
    const float* x = (const float*)d_in[0];
    const float* etype = (const float*)d_in[1];
    const int* mask = (const int*)d_in[2];
    const float* Wq = (const float*)d_in[3];
    const float* bq = (const float*)d_in[4];
    const float* Wk = (const float*)d_in[5];
    const float* bk = (const float*)d_in[6];
    const float* Wv = (const float*)d_in[7];
    const float* bv = (const float*)d_in[8];
    float* out = (float*)d_out;

    char* ws = (char*)d_ws;
    _Float16* xh = (_Float16*)(ws + 0);
    _Float16* wT = (_Float16*)(ws + 8388608);
    _Float16* Qh = (_Float16*)(ws + 9961472);
    _Float16* Kh = (_Float16*)(ws + 18350080);
    _Float16* Vt = (_Float16*)(ws + 26738688);

    cvt_f32_to_f16<<<2048, 256, 0, stream>>>(x, xh, (Bn * Sn * Fn) / 4);
    cvt_wT<<<dim3(32, 32, 3), dim3(16, 16), 0, stream>>>(Wq, Wk, Wv, wT);
    qkv_gemm<<<dim3(64, 4, 3), 256, 0, stream>>>(xh, wT, bq, bk, bv, Qh, Kh, Vt);
    attn<<<1024, 256, 0, stream>>>(Qh, Kh, Vt, mask, etype, out);
}

// Round 5
// 197.894 us; speedup vs baseline: 2.3737x; 2.3737x over previous
//
#include <hip/hip_runtime.h>
#include <hip/hip_bf16.h>

// B=4, S=2048, F=512, E=512, H=8, DH=64
// Pipeline: f32->f16 cast, LDS-staged fused QKV GEMM with coalesced packed-tile
// epilogue, flash attention with LDS-staged K/V (double-buffered) and
// swapped-operand QK^T (register-local softmax).
// Workspace:
//   xh  [8192][512] f16   @ 0        (8 MB)
//   wT  [3][512][512] f16 @ 8388608  (1.5 MB)  wT[z][n][k] = W_z[k][n]
//   Qh  @ 9961472  (8 MB)  per head 256KB: [s][64] f16 linear
//   Kpk @ 18350080 (8 MB)  per head 32 tiles x 8KB: [key&63][128B], byte ^= ((key&7)<<4)
//   Vpk @ 26738688 (8 MB)  per head 32 tiles x 8KB: [d][128B keys], byte ^= ((d&7)<<4)

typedef _Float16 f16x4 __attribute__((ext_vector_type(4)));
typedef _Float16 f16x8 __attribute__((ext_vector_type(8)));
typedef float f32x4 __attribute__((ext_vector_type(4)));

#define MFMA16(a, b, c) __builtin_amdgcn_mfma_f32_16x16x16f16((a), (b), (c), 0, 0, 0)
#define MFMA32(a, b, c) __builtin_amdgcn_mfma_f32_16x16x32_f16((a), (b), (c), 0, 0, 0)
#define GLDS16(g, l)                                                                     \
    __builtin_amdgcn_global_load_lds((const __attribute__((address_space(1))) void*)(g), \
                                     (__attribute__((address_space(3))) void*)(l), 16, 0, 0)

constexpr int Bn = 4, Sn = 2048, Fn = 512, En = 512, Hn = 8, DHn = 64;

__global__ void cvt_f32_to_f16(const float* __restrict__ in, _Float16* __restrict__ out, int n4) {
    int i = blockIdx.x * blockDim.x + threadIdx.x;
    int stride = gridDim.x * blockDim.x;
    for (; i < n4; i += stride) {
        float4 v = reinterpret_cast<const float4*>(in)[i];
        f16x4 o = { (_Float16)v.x, (_Float16)v.y, (_Float16)v.z, (_Float16)v.w };
        reinterpret_cast<f16x4*>(out)[i] = o;
    }
}

// wT[z][n][k] = W_z[k][n]
__global__ void cvt_wT(const float* __restrict__ Wq, const float* __restrict__ Wk,
                       const float* __restrict__ Wv, _Float16* __restrict__ out) {
    const int z = blockIdx.z;
    const float* W = (z == 0) ? Wq : ((z == 1) ? Wk : Wv);
    _Float16* o = out + (size_t)z * Fn * En;
    __shared__ float tile[16][17];
    int n = blockIdx.x * 16 + threadIdx.x;
    int k = blockIdx.y * 16 + threadIdx.y;
    tile[threadIdx.y][threadIdx.x] = W[k * En + n];
    __syncthreads();
    int n2 = blockIdx.x * 16 + threadIdx.y;
    int k2 = blockIdx.y * 16 + threadIdx.x;
    o[(size_t)n2 * Fn + k2] = (_Float16)tile[threadIdx.x][threadIdx.y];
}

// Fused QKV GEMM: 128x128 tile, BK=64, global_load_lds staging (m97), then
// LDS-transpose epilogue with fully coalesced 16B stores into packed layouts.
// grid (64, 4, 3), block 256 (4 waves, 64x64 quadrants).
__global__ __launch_bounds__(256) void qkv_gemm(
    const _Float16* __restrict__ xh, const _Float16* __restrict__ wT,
    const float* __restrict__ bq, const float* __restrict__ bk, const float* __restrict__ bv,
    char* __restrict__ Qh, char* __restrict__ Kpk, char* __restrict__ Vpk) {
    const int z = blockIdx.z;
    const _Float16* Wz = wT + (size_t)z * Fn * En;
    const float* bias = (z == 0) ? bq : ((z == 1) ? bk : bv);

    const int tid = threadIdx.x;
    const int wave = tid >> 6, lane = tid & 63;
    const int lr = lane & 15, hi = lane >> 4;
    const int wr = wave >> 1, wc = wave & 1;
    const int m0 = blockIdx.x * 128;
    const int n0 = blockIdx.y * 128;

    __shared__ __align__(16) char smem[34816];  // staging 32KB | epilogue f16[128][136]
    char* As = smem;
    char* Bs = smem + 16384;

    f32x4 acc[4][4] = {};

    const int inrow = (tid & 7) * 16;
    const int rowb = tid >> 3;

    const char* xg = (const char*)xh;
    const char* wg = (const char*)Wz;

    for (int t = 0; t < 8; ++t) {
        const int k0b = t * 128;
        __syncthreads();
#pragma unroll
        for (int it = 0; it < 4; ++it) {
            const int row = rowb + it * 32;
            const int srccol = inrow ^ ((row & 7) << 4);
            const char* ga = xg + (size_t)(m0 + row) * 1024 + k0b + srccol;
            const char* gb = wg + (size_t)(n0 + row) * 1024 + k0b + srccol;
            const int ldso = (it * 256 + tid) * 16;
            GLDS16(ga, As + ldso);
            GLDS16(gb, Bs + ldso);
        }
        asm volatile("s_waitcnt vmcnt(0)" ::: "memory");
        __syncthreads();
#pragma unroll
        for (int ks = 0; ks < 2; ++ks) {
            f16x8 af[4], bf[4];
            const int kb = ks * 64 + hi * 16;
#pragma unroll
            for (int mt = 0; mt < 4; ++mt) {
                const int row = wr * 64 + mt * 16 + lr;
                af[mt] = *reinterpret_cast<const f16x8*>(As + row * 128 + (kb ^ ((row & 7) << 4)));
            }
#pragma unroll
            for (int nt = 0; nt < 4; ++nt) {
                const int row = wc * 64 + nt * 16 + lr;
                bf[nt] = *reinterpret_cast<const f16x8*>(Bs + row * 128 + (kb ^ ((row & 7) << 4)));
            }
#pragma unroll
            for (int mt = 0; mt < 4; ++mt)
#pragma unroll
                for (int nt = 0; nt < 4; ++nt)
                    acc[mt][nt] = MFMA32(af[mt], bf[nt], acc[mt][nt]);
        }
    }

    // ---- epilogue: acc (+bias, ->f16) into LDS tile [128 s][136 c], then coalesced out
    __syncthreads();
    _Float16* tl = (_Float16*)smem;
    {
        const int cb = wc * 64 + lr;
#pragma unroll
        for (int mt = 0; mt < 4; ++mt) {
            const int sb = wr * 64 + mt * 16 + hi * 4;
#pragma unroll
            for (int nt = 0; nt < 4; ++nt) {
                const int c = cb + nt * 16;
                const float bz = bias[n0 + c];
#pragma unroll
                for (int r = 0; r < 4; ++r)
                    tl[(sb + r) * 136 + c] = (_Float16)(acc[mt][nt][r] + bz);
            }
        }
    }
    __syncthreads();

    const int b8 = (m0 >> 11) * 8;        // batch*8
    const int h0 = n0 >> 6;               // first head of this col-block
    const int kt0 = (m0 & 2047) >> 6;     // first 64-key tile of this row-block
    char* outz = (z == 0) ? Qh : ((z == 1) ? Kpk : Vpk);

#pragma unroll
    for (int chunk = 0; chunk < 4; ++chunk) {
        const int hh = chunk >> 1, T = chunk & 1;
        char* base = outz + (size_t)(b8 + h0 + hh) * 262144 + (size_t)(kt0 + T) * 8192;
#pragma unroll
        for (int j = 0; j < 2; ++j) {
            const int g = tid * 16 + j * 4096;
            f16x8 val;
            if (z == 0) {         // Qh: [s][64] f16 linear
                const int s = T * 64 + (g >> 7), db = g & 127;
                val = *reinterpret_cast<const f16x8*>(&tl[s * 136 + hh * 64 + (db >> 1)]);
            } else if (z == 1) {  // Kpk: row=key, col bytes d*2 ^ ((key&7)<<4)
                const int r = g >> 7;
                const int colb = (g & 127) ^ ((r & 7) << 4);
                val = *reinterpret_cast<const f16x8*>(&tl[(T * 64 + r) * 136 + hh * 64 + (colb >> 1)]);
            } else {              // Vpk: row=d, col bytes key*2 ^ ((d&7)<<4)  (transpose)
                const int d = g >> 7;
                const int k0 = ((g & 127) ^ ((d & 7) << 4)) >> 1;
#pragma unroll
                for (int jj = 0; jj < 8; ++jj)
                    val[jj] = tl[(T * 64 + k0 + jj) * 136 + hh * 64 + d];
            }
            *reinterpret_cast<f16x8*>(base + g) = val;
        }
    }
}

// Flash attention: grid 1024 1D (bid%32 = head -> XCD locality), 4 waves x 16 q-rows.
// K/V tiles staged in LDS (double-buffered 2x16KB) via coalesced global_load_lds from
// the packed pre-swizzled layouts; fragments via swizzled ds_read. Softmax lane-local.
__global__ __launch_bounds__(256, 4) void attn(
    const _Float16* __restrict__ Qh, const char* __restrict__ Kpk,
    const char* __restrict__ Vpk, const int* __restrict__ mask,
    const float* __restrict__ etype, float* __restrict__ out) {
    const int bid = blockIdx.x;
    const int bh = bid & 31, qb = bid >> 5;
    const int b = bh >> 3, h = bh & 7;
    const int tid = threadIdx.x;
    const int wave = tid >> 6, lane = tid & 63;
    const int lr = lane & 15, hi = lane >> 4;
    const int q0 = qb * 64 + wave * 16;

    const _Float16* Qb = Qh + (size_t)bh * Sn * DHn;
    const char* Kb = Kpk + (size_t)bh * 262144;
    const char* Vb = Vpk + (size_t)bh * 262144;
    const int* mb = mask + b * Sn;

    constexpr float CSC = 0.18033688011112042f;  // 0.125 * log2(e)
    constexpr int NT = Sn / 64;

    __shared__ __align__(16) char kv[2][16384];  // [buf][ K 8KB | V 8KB ]

    // stage tile 0
#pragma unroll
    for (int j = 0; j < 2; ++j) {
        GLDS16(Kb + tid * 16 + j * 4096, kv[0] + tid * 16 + j * 4096);
        GLDS16(Vb + tid * 16 + j * 4096, kv[0] + 8192 + tid * 16 + j * 4096);
    }

    // Q fragment: col = l&15 = q-row, k = ks*32 + hi*8 + e; add etype, prescale
    f16x8 qf[2];
#pragma unroll
    for (int ks = 0; ks < 2; ++ks) {
        const f16x8 qh = *reinterpret_cast<const f16x8*>(Qb + (q0 + lr) * DHn + ks * 32 + hi * 8);
        const float* ep = etype + ((size_t)(b * Sn) + q0 + lr) * En + h * DHn + ks * 32 + hi * 8;
        const f32x4 e0 = *reinterpret_cast<const f32x4*>(ep);
        const f32x4 e1 = *reinterpret_cast<const f32x4*>(ep + 4);
        f16x8 q;
#pragma unroll
        for (int j = 0; j < 4; ++j) q[j] = (_Float16)(((float)qh[j] + e0[j]) * CSC);
#pragma unroll
        for (int j = 0; j < 4; ++j) q[4 + j] = (_Float16)(((float)qh[4 + j] + e1[j]) * CSC);
        qf[ks] = q;
    }

    f32x4 oaccT[4] = {};  // [dt]: row = d-local (hi*4+r), col = q-row (l&15)
    f32x4 osum = {};      // ones-row MFMA accumulator = running row-sum
    float mrun = -3e38f;
    const f16x4 onev = {(_Float16)1.f, (_Float16)1.f, (_Float16)1.f, (_Float16)1.f};

    asm volatile("s_waitcnt vmcnt(0)" ::: "memory");
    __syncthreads();

    for (int t = 0; t < NT; ++t) {
        const char* cbuf = kv[t & 1];
        char* nbuf = kv[(t + 1) & 1];

        // issue next-tile staging (in flight under this tile's compute)
        const size_t nto = (size_t)((t + 1) & (NT - 1)) * 8192;
#pragma unroll
        for (int j = 0; j < 2; ++j) {
            GLDS16(Kb + nto + tid * 16 + j * 4096, nbuf + tid * 16 + j * 4096);
            GLDS16(Vb + nto + tid * 16 + j * 4096, nbuf + 8192 + tid * 16 + j * 4096);
        }

        const int key0 = t * 64;
        int4 km[4];
#pragma unroll
        for (int kt = 0; kt < 4; ++kt)
            km[kt] = *reinterpret_cast<const int4*>(mb + key0 + kt * 16 + hi * 4);

        // K fragments from LDS (swizzled), S^T = K·Q^T
        f16x8 kf[4][2];
#pragma unroll
        for (int kt = 0; kt < 4; ++kt)
#pragma unroll
            for (int ks = 0; ks < 2; ++ks)
                kf[kt][ks] = *reinterpret_cast<const f16x8*>(
                    cbuf + (kt * 16 + lr) * 128 + ((ks * 64 + hi * 16) ^ ((lr & 7) << 4)));

        f32x4 scT[4] = {};
#pragma unroll
        for (int ks = 0; ks < 2; ++ks)
#pragma unroll
            for (int kt = 0; kt < 4; ++kt)
                scT[kt] = MFMA32(kf[kt][ks], qf[ks], scT[kt]);

        // key-mask -> -1e30
        scT[0][0] = km[0].x ? scT[0][0] : -1e30f; scT[0][1] = km[0].y ? scT[0][1] : -1e30f;
        scT[0][2] = km[0].z ? scT[0][2] : -1e30f; scT[0][3] = km[0].w ? scT[0][3] : -1e30f;
        scT[1][0] = km[1].x ? scT[1][0] : -1e30f; scT[1][1] = km[1].y ? scT[1][1] : -1e30f;
        scT[1][2] = km[1].z ? scT[1][2] : -1e30f; scT[1][3] = km[1].w ? scT[1][3] : -1e30f;
        scT[2][0] = km[2].x ? scT[2][0] : -1e30f; scT[2][1] = km[2].y ? scT[2][1] : -1e30f;
        scT[2][2] = km[2].z ? scT[2][2] : -1e30f; scT[2][3] = km[2].w ? scT[2][3] : -1e30f;
        scT[3][0] = km[3].x ? scT[3][0] : -1e30f; scT[3][1] = km[3].y ? scT[3][1] : -1e30f;
        scT[3][2] = km[3].z ? scT[3][2] : -1e30f; scT[3][3] = km[3].w ? scT[3][3] : -1e30f;

        // row max: 16 lane-local + 2 shuffles
        float mx = -3e38f;
#pragma unroll
        for (int kt = 0; kt < 4; ++kt)
#pragma unroll
            for (int r = 0; r < 4; ++r) mx = fmaxf(mx, scT[kt][r]);
        mx = fmaxf(mx, __shfl_xor(mx, 16));
        mx = fmaxf(mx, __shfl_xor(mx, 32));

        // defer-max (THR=8)
        if (!__all(mx <= mrun + 8.0f)) {
            const float mnew = fmaxf(mrun, mx);
            const float al = exp2f(mrun - mnew);
            mrun = mnew;
#pragma unroll
            for (int dt = 0; dt < 4; ++dt) oaccT[dt] *= al;
            osum *= al;
        }

        // P = exp2(S - m) -> f16 (register-local)
        f16x4 pa[4];
#pragma unroll
        for (int kt = 0; kt < 4; ++kt) {
            f16x4 p;
#pragma unroll
            for (int r = 0; r < 4; ++r) p[r] = (_Float16)exp2f(scT[kt][r] - mrun);
            pa[kt] = p;
        }

        // V fragments from LDS (swizzled), O^T += V^T·P^T ; ones-row sum on MFMA pipe
#pragma unroll
        for (int ks = 0; ks < 4; ++ks) {
#pragma unroll
            for (int dt = 0; dt < 4; ++dt) {
                const f16x4 vf = *reinterpret_cast<const f16x4*>(
                    cbuf + 8192 + (dt * 16 + lr) * 128 + ((ks * 32 + hi * 8) ^ ((lr & 7) << 4)));
                oaccT[dt] = MFMA16(vf, pa[ks], oaccT[dt]);
            }
            osum = MFMA16(onev, pa[ks], osum);
        }

        asm volatile("s_waitcnt vmcnt(0)" ::: "memory");
        __syncthreads();
    }

    // epilogue: query-mask zeroing + 1/sum
    const int srow = q0 + lr;
    const float inv = (mb[srow] != 0) ? 1.0f / osum[0] : 0.0f;
#pragma unroll
    for (int dt = 0; dt < 4; ++dt) {
        f32x4 o = oaccT[dt] * inv;
        *reinterpret_cast<f32x4*>(out + ((size_t)(b * Sn + srow)) * En + h * DHn + dt * 16 + hi * 4) = o;
    }
}

extern "C" void kernel_launch(void* const* d_in, const int* in_sizes, int n_in,
                              void* d_out, int out_size, void* d_ws, size_t ws_size,
                              hipStream_t stream) {
    const float* x = (const float*)d_in[0];
    const float* etype = (const float*)d_in[1];
    const int* mask = (const int*)d_in[2];
    const float* Wq = (const float*)d_in[3];
    const float* bq = (const float*)d_in[4];
    const float* Wk = (const float*)d_in[5];
    const float* bk = (const float*)d_in[6];
    const float* Wv = (const float*)d_in[7];
    const float* bv = (const float*)d_in[8];
    float* out = (float*)d_out;

    char* ws = (char*)d_ws;
    _Float16* xh = (_Float16*)(ws + 0);
    _Float16* wT = (_Float16*)(ws + 8388608);
    char* Qh = ws + 9961472;
    char* Kpk = ws + 18350080;
    char* Vpk = ws + 26738688;

    cvt_f32_to_f16<<<2048, 256, 0, stream>>>(x, xh, (Bn * Sn * Fn) / 4);
    cvt_wT<<<dim3(32, 32, 3), dim3(16, 16), 0, stream>>>(Wq, Wk, Wv, wT);
    qkv_gemm<<<dim3(64, 4, 3), 256, 0, stream>>>(xh, wT, bq, bk, bv, Qh, Kpk, Vpk);
    attn<<<1024, 256, 0, stream>>>((const _Float16*)Qh, Kpk, Vpk, mask, etype, out);
}

// Round 7
// 189.883 us; speedup vs baseline: 2.4739x; 1.0422x over previous
//
#include <hip/hip_runtime.h>
#include <hip/hip_bf16.h>

// B=4, S=2048, F=512, E=512, H=8, DH=64
// Pipeline: f32->f16 cast, W transpose+cast, fused QKV GEMM (LDS-staged, packed
// fragment-order epilogue), flash attention (LDS double-buffered K/V in fragment
// order -> zero-conflict zero-VALU ds_reads; mask folded as additive bias into
// the MFMA accumulator init; swapped-operand QK^T keeps softmax lane-local).
// Workspace:
//   xh  [8192][512] f16   @ 0        (8 MB)
//   wT  [3][512][512] f16 @ 8388608  (1.5 MB)  wT[z][n][k] = W_z[k][n]
//   Qh  @ 9961472  (8 MB)  per head 32 tiles x 8KB: [s(64)][d(64)] f16 linear
//   Kpk @ 18350080 (8 MB)  per head 32 tiles x 8KB, fragment order:
//        byte ((kt*2+ks)*64+lane)*16 = K[key=kt*16+(lane&15)][d=ks*32+(lane>>4)*8 +0..7]
//   Vpk @ 26738688 (8 MB)  per head 32 tiles x 8KB, fragment order:
//        byte ((ks*2+dp)*64+lane)*16 = V[d=(dp*2+i)*16+(lane&15)][key=ks*16+(lane>>4)*4 +0..3], i=0,1

typedef _Float16 f16x4 __attribute__((ext_vector_type(4)));
typedef _Float16 f16x8 __attribute__((ext_vector_type(8)));
typedef float f32x4 __attribute__((ext_vector_type(4)));

#define MFMA16(a, b, c) __builtin_amdgcn_mfma_f32_16x16x16f16((a), (b), (c), 0, 0, 0)
#define MFMA32(a, b, c) __builtin_amdgcn_mfma_f32_16x16x32_f16((a), (b), (c), 0, 0, 0)
#define GLDS16(g, l)                                                                     \
    __builtin_amdgcn_global_load_lds((const __attribute__((address_space(1))) void*)(g), \
                                     (__attribute__((address_space(3))) void*)(l), 16, 0, 0)

constexpr int Bn = 4, Sn = 2048, Fn = 512, En = 512, Hn = 8, DHn = 64;

__global__ void cvt_f32_to_f16(const float* __restrict__ in, _Float16* __restrict__ out, int n4) {
    int i = blockIdx.x * blockDim.x + threadIdx.x;
    int stride = gridDim.x * blockDim.x;
    for (; i < n4; i += stride) {
        float4 v = reinterpret_cast<const float4*>(in)[i];
        f16x4 o = { (_Float16)v.x, (_Float16)v.y, (_Float16)v.z, (_Float16)v.w };
        reinterpret_cast<f16x4*>(out)[i] = o;
    }
}

// wT[z][n][k] = W_z[k][n]
__global__ void cvt_wT(const float* __restrict__ Wq, const float* __restrict__ Wk,
                       const float* __restrict__ Wv, _Float16* __restrict__ out) {
    const int z = blockIdx.z;
    const float* W = (z == 0) ? Wq : ((z == 1) ? Wk : Wv);
    _Float16* o = out + (size_t)z * Fn * En;
    __shared__ float tile[16][17];
    int n = blockIdx.x * 16 + threadIdx.x;
    int k = blockIdx.y * 16 + threadIdx.y;
    tile[threadIdx.y][threadIdx.x] = W[k * En + n];
    __syncthreads();
    int n2 = blockIdx.x * 16 + threadIdx.y;
    int k2 = blockIdx.y * 16 + threadIdx.x;
    o[(size_t)n2 * Fn + k2] = (_Float16)tile[threadIdx.x][threadIdx.y];
}

// Fused QKV GEMM: 128x64 tiles, BK=64, global_load_lds staging, swizzled LDS
// epilogue tile, packed fragment-order outputs. grid (64, 8, 3), 6 blocks/CU.
__global__ __launch_bounds__(256, 6) void qkv_gemm(
    const _Float16* __restrict__ xh, const _Float16* __restrict__ wT,
    const float* __restrict__ bq, const float* __restrict__ bk, const float* __restrict__ bv,
    char* __restrict__ Qh, char* __restrict__ Kpk, char* __restrict__ Vpk) {
    const int z = blockIdx.z;
    const _Float16* Wz = wT + (size_t)z * Fn * En;
    const float* bias = (z == 0) ? bq : ((z == 1) ? bk : bv);

    const int tid = threadIdx.x;
    const int wave = tid >> 6, lane = tid & 63;
    const int lr = lane & 15, hi = lane >> 4;
    const int wr = wave >> 1, wn = wave & 1;
    const int m0 = blockIdx.x * 128;
    const int n0 = blockIdx.y * 64;

    __shared__ __align__(16) char smem[24576];
    char* As = smem;            // 16 KB: [128 rows][128 B], swizzled
    char* Bs = smem + 16384;    // 8 KB:  [64 rows][128 B], swizzled

    f32x4 acc[4][2] = {};
    const int inrow = (tid & 7) * 16;
    const int rowb = tid >> 3;
    const char* xg = (const char*)xh;
    const char* wg = (const char*)Wz;

    for (int t = 0; t < 8; ++t) {
        const int k0b = t * 128;
        __syncthreads();
#pragma unroll
        for (int it = 0; it < 4; ++it) {
            const int row = rowb + it * 32;
            const int sc = inrow ^ ((row & 7) << 4);
            GLDS16(xg + (size_t)(m0 + row) * 1024 + k0b + sc, As + it * 4096 + tid * 16);
            if (it < 2)
                GLDS16(wg + (size_t)(n0 + row) * 1024 + k0b + sc, Bs + it * 4096 + tid * 16);
        }
        asm volatile("s_waitcnt vmcnt(0)" ::: "memory");
        __syncthreads();
#pragma unroll
        for (int ks = 0; ks < 2; ++ks) {
            const int kb = (ks * 64 + hi * 16) ^ ((lr & 7) << 4);
            f16x8 af[4], bf[2];
#pragma unroll
            for (int mt = 0; mt < 4; ++mt)
                af[mt] = *reinterpret_cast<const f16x8*>(As + (wr * 64 + mt * 16 + lr) * 128 + kb);
#pragma unroll
            for (int nt = 0; nt < 2; ++nt)
                bf[nt] = *reinterpret_cast<const f16x8*>(Bs + (wn * 32 + nt * 16 + lr) * 128 + kb);
#pragma unroll
            for (int mt = 0; mt < 4; ++mt)
#pragma unroll
                for (int nt = 0; nt < 2; ++nt)
                    acc[mt][nt] = MFMA32(af[mt], bf[nt], acc[mt][nt]);
        }
    }

    // epilogue: acc(+bias)->f16 swizzled LDS tile [128 s][64 c], then packed stores
    __syncthreads();
    {
        const int cb = wn * 32 + lr;
#pragma unroll
        for (int mt = 0; mt < 4; ++mt) {
            const int sb = wr * 64 + mt * 16 + hi * 4;
#pragma unroll
            for (int nt = 0; nt < 2; ++nt) {
                const int c = cb + nt * 16;
                const float bz = bias[n0 + c];
#pragma unroll
                for (int r = 0; r < 4; ++r) {
                    const int s = sb + r;
                    *reinterpret_cast<_Float16*>(smem + s * 128 + ((c * 2) ^ ((s & 7) << 4))) =
                        (_Float16)(acc[mt][nt][r] + bz);
                }
            }
        }
    }
    __syncthreads();

    const int bb = m0 >> 11;
    const int bh = bb * 8 + blockIdx.y;
    const int kt0 = (m0 & 2047) >> 6;
    char* outz = (z == 0) ? Qh : ((z == 1) ? Kpk : Vpk);
    char* hb = outz + (size_t)bh * 262144 + (size_t)kt0 * 8192;
    const char* sm = (const char*)smem;

#pragma unroll
    for (int j = 0; j < 4; ++j) {
        const int g = tid * 16 + j * 4096;
        const int T = g >> 13, g13 = g & 8191;
        f16x8 val;
        if (z == 0) {  // Q: [s][64] linear
            const int s = T * 64 + (g13 >> 7);
            val = *reinterpret_cast<const f16x8*>(sm + s * 128 + ((g13 & 127) ^ ((s & 7) << 4)));
        } else if (z == 1) {  // K fragment order
            const int chunk = g13 >> 10, l2 = (g13 >> 4) & 63;
            const int s = T * 64 + (chunk >> 1) * 16 + (l2 & 15);
            const int db = (chunk & 1) * 64 + (l2 >> 4) * 16;
            val = *reinterpret_cast<const f16x8*>(sm + s * 128 + (db ^ ((s & 7) << 4)));
        } else {  // V fragment order (transpose via scalar reads)
            const int chunk = g13 >> 10, l2 = (g13 >> 4) & 63;
            const int ks = chunk >> 1, dp = chunk & 1;
            const int lr2 = l2 & 15, hi2 = l2 >> 4;
#pragma unroll
            for (int i = 0; i < 8; ++i) {
                const int d = (dp * 2 + (i >> 2)) * 16 + lr2;
                const int s = T * 64 + ks * 16 + hi2 * 4 + (i & 3);
                val[i] = *reinterpret_cast<const _Float16*>(sm + s * 128 + ((d * 2) ^ ((s & 7) << 4)));
            }
        }
        *reinterpret_cast<f16x8*>(hb + g) = val;
    }
}

// Flash attention. grid 1024 (bid%32 = head -> XCD L2 locality), 4 waves x 16 q.
// K/V double-buffered in LDS in fragment order (lane-linear ds_read_b128, zero
// conflicts / zero addr-VALU); mask bias staged in LDS, folded into MFMA C-init.
__global__ __launch_bounds__(256, 4) void attn(
    const _Float16* __restrict__ Qh, const char* __restrict__ Kpk,
    const char* __restrict__ Vpk, const int* __restrict__ mask,
    const float* __restrict__ etype, float* __restrict__ out) {
    const int bid = blockIdx.x;
    const int bh = bid & 31, qb = bid >> 5;
    const int b = bh >> 3, h = bh & 7;
    const int tid = threadIdx.x;
    const int wave = tid >> 6, lane = tid & 63;
    const int lr = lane & 15, hi = lane >> 4;
    const int q0 = qb * 64 + wave * 16;

    const _Float16* Qb = Qh + (size_t)bh * Sn * DHn;
    const char* Kb = Kpk + (size_t)bh * 262144;
    const char* Vg = Vpk + (size_t)bh * 262144;
    const int* mb = mask + b * Sn;

    __shared__ __align__(16) char lds[40960];  // [2][16KB] K|V double buffer; 8KB bias

    // stage mask ints (converted to f32 bias in place below) + tile 0 K/V
    {
        const char* ms = (const char*)(mask + b * Sn);
        GLDS16(ms + tid * 16, lds + 32768 + tid * 16);
        GLDS16(ms + tid * 16 + 4096, lds + 32768 + tid * 16 + 4096);
        GLDS16(Kb + tid * 16, lds + tid * 16);
        GLDS16(Kb + tid * 16 + 4096, lds + tid * 16 + 4096);
        GLDS16(Vg + tid * 16, lds + 8192 + tid * 16);
        GLDS16(Vg + tid * 16 + 4096, lds + 8192 + tid * 16 + 4096);
    }

    // Q fragment: col = l&15 = q-row, k = ks*32 + hi*8 + e; add etype, prescale
    constexpr float CSC = 0.18033688011112042f;  // 0.125 * log2(e)
    f16x8 qf[2];
#pragma unroll
    for (int ks = 0; ks < 2; ++ks) {
        const f16x8 qh = *reinterpret_cast<const f16x8*>(Qb + (q0 + lr) * DHn + ks * 32 + hi * 8);
        const float* ep = etype + ((size_t)(b * Sn) + q0 + lr) * En + h * DHn + ks * 32 + hi * 8;
        const f32x4 e0 = *reinterpret_cast<const f32x4*>(ep);
        const f32x4 e1 = *reinterpret_cast<const f32x4*>(ep + 4);
        f16x8 q;
#pragma unroll
        for (int j = 0; j < 4; ++j) q[j] = (_Float16)(((float)qh[j] + e0[j]) * CSC);
#pragma unroll
        for (int j = 0; j < 4; ++j) q[4 + j] = (_Float16)(((float)qh[4 + j] + e1[j]) * CSC);
        qf[ks] = q;
    }

    f32x4 oaccT[4] = {};  // [dt]: row = d-local (hi*4+r), col = q-row (l&15)
    f32x4 osum = {};
    float mrun = -3e38f;
    const f16x4 onev = {(_Float16)1.f, (_Float16)1.f, (_Float16)1.f, (_Float16)1.f};

    asm volatile("s_waitcnt vmcnt(0)" ::: "memory");
    __syncthreads();

    // convert mask ints -> f32 bias in place (0 / -1e30)
    {
        int4 a = *reinterpret_cast<const int4*>(lds + 32768 + tid * 16);
        int4 c = *reinterpret_cast<const int4*>(lds + 32768 + tid * 16 + 4096);
        __syncthreads();
        f32x4 fa = {a.x ? 0.f : -1e30f, a.y ? 0.f : -1e30f, a.z ? 0.f : -1e30f, a.w ? 0.f : -1e30f};
        f32x4 fc = {c.x ? 0.f : -1e30f, c.y ? 0.f : -1e30f, c.z ? 0.f : -1e30f, c.w ? 0.f : -1e30f};
        *reinterpret_cast<f32x4*>(lds + 32768 + tid * 16) = fa;
        *reinterpret_cast<f32x4*>(lds + 32768 + tid * 16 + 4096) = fc;
        __syncthreads();
    }

    const char* kvr = lds + lane * 16;       // fragment read base (per-lane)
    const char* pmb = lds + 32768 + hi * 16; // bias read base (broadcast in 16-group)

    for (int tp = 0; tp < 16; ++tp) {
        const int tb = tp * 512;  // byte offset of this tile-pair's bias (128 keys * 4B)
#pragma unroll
        for (int u = 0; u < 2; ++u) {
            const int t = tp * 2 + u;
            // stage next tile into the other buffer
            const size_t nto = (size_t)((t + 1) & 31) * 8192;
            char* nb = lds + (u ^ 1) * 16384;
            GLDS16(Kb + nto + tid * 16, nb + tid * 16);
            GLDS16(Kb + nto + tid * 16 + 4096, nb + tid * 16 + 4096);
            GLDS16(Vg + nto + tid * 16, nb + 8192 + tid * 16);
            GLDS16(Vg + nto + tid * 16 + 4096, nb + 8192 + tid * 16 + 4096);

            // S^T accumulator initialized from mask bias: key = t*64 + kt*16 + hi*4 + r
            f32x4 scT[4];
#pragma unroll
            for (int kt = 0; kt < 4; ++kt)
                scT[kt] = *reinterpret_cast<const f32x4*>(pmb + tb + u * 256 + kt * 64);

            const char* cb = kvr + u * 16384;
#pragma unroll
            for (int ks = 0; ks < 2; ++ks)
#pragma unroll
                for (int kt = 0; kt < 4; ++kt) {
                    const f16x8 kf = *reinterpret_cast<const f16x8*>(cb + (kt * 2 + ks) * 1024);
                    scT[kt] = MFMA32(kf, qf[ks], scT[kt]);
                }

            // row max: 15 lane-local fmax + 2 shuffles
            float mx = fmaxf(fmaxf(scT[0][0], scT[0][1]), fmaxf(scT[0][2], scT[0][3]));
            mx = fmaxf(mx, fmaxf(fmaxf(scT[1][0], scT[1][1]), fmaxf(scT[1][2], scT[1][3])));
            mx = fmaxf(mx, fmaxf(fmaxf(scT[2][0], scT[2][1]), fmaxf(scT[2][2], scT[2][3])));
            mx = fmaxf(mx, fmaxf(fmaxf(scT[3][0], scT[3][1]), fmaxf(scT[3][2], scT[3][3])));
            mx = fmaxf(mx, __shfl_xor(mx, 16));
            mx = fmaxf(mx, __shfl_xor(mx, 32));

            // defer-max (THR=8)
            if (!__all(mx <= mrun + 8.0f)) {
                const float mnew = fmaxf(mrun, mx);
                const float al = exp2f(mrun - mnew);
                mrun = mnew;
#pragma unroll
                for (int dt = 0; dt < 4; ++dt) oaccT[dt] *= al;
                osum *= al;
            }

            // P = exp2(S - m) -> f16 (register-local)
            f16x4 pa[4];
#pragma unroll
            for (int kt = 0; kt < 4; ++kt) {
                f16x4 p;
#pragma unroll
                for (int r = 0; r < 4; ++r) p[r] = (_Float16)exp2f(scT[kt][r] - mrun);
                pa[kt] = p;
            }

            // PV: V fragments lane-linear; O^T += V^T.P^T ; ones-row sum on MFMA pipe
#pragma unroll
            for (int ks = 0; ks < 4; ++ks) {
#pragma unroll
                for (int dp = 0; dp < 2; ++dp) {
                    const f16x8 vv = *reinterpret_cast<const f16x8*>(cb + 8192 + (ks * 2 + dp) * 1024);
                    const f16x4 v0 = {vv[0], vv[1], vv[2], vv[3]};
                    const f16x4 v1 = {vv[4], vv[5], vv[6], vv[7]};
                    oaccT[dp * 2] = MFMA16(v0, pa[ks], oaccT[dp * 2]);
                    oaccT[dp * 2 + 1] = MFMA16(v1, pa[ks], oaccT[dp * 2 + 1]);
                }
                osum = MFMA16(onev, pa[ks], osum);
            }

            asm volatile("s_waitcnt vmcnt(0)" ::: "memory");
            __syncthreads();
        }
    }

    // epilogue: query-mask zeroing + 1/sum
    const int srow = q0 + lr;
    const float inv = (mb[srow] != 0) ? 1.0f / osum[0] : 0.0f;
#pragma unroll
    for (int dt = 0; dt < 4; ++dt) {
        f32x4 o = oaccT[dt] * inv;
        *reinterpret_cast<f32x4*>(out + ((size_t)(b * Sn + srow)) * En + h * DHn + dt * 16 + hi * 4) = o;
    }
}

extern "C" void kernel_launch(void* const* d_in, const int* in_sizes, int n_in,
                              void* d_out, int out_size, void* d_ws, size_t ws_size,
                              hipStream_t stream) {
    const float* x = (const float*)d_in[0];
    const float* etype = (const float*)d_in[1];
    const int* mask = (const int*)d_in[2];
    const float* Wq = (const float*)d_in[3];
    const float* bq = (const float*)d_in[4];
    const float* Wk = (const float*)d_in[5];
    const float* bk = (const float*)d_in[6];
    const float* Wv = (const float*)d_in[7];
    const float* bv = (const float*)d_in[8];
    float* out = (float*)d_out;

    char* ws = (char*)d_ws;
    _Float16* xh = (_Float16*)(ws + 0);
    _Float16* wT = (_Float16*)(ws + 8388608);
    char* Qh = ws + 9961472;
    char* Kpk = ws + 18350080;
    char* Vpk = ws + 26738688;

    cvt_f32_to_f16<<<2048, 256, 0, stream>>>(x, xh, (Bn * Sn * Fn) / 4);
    cvt_wT<<<dim3(32, 32, 3), dim3(16, 16), 0, stream>>>(Wq, Wk, Wv, wT);
    qkv_gemm<<<dim3(64, 8, 3), 256, 0, stream>>>(xh, wT, bq, bk, bv, Qh, Kpk, Vpk);
    attn<<<1024, 256, 0, stream>>>((const _Float16*)Qh, Kpk, Vpk, mask, etype, out);
}

// Round 9
// 181.365 us; speedup vs baseline: 2.5901x; 1.0470x over previous
//
#include <hip/hip_runtime.h>
#include <hip/hip_bf16.h>

// B=4, S=2048, F=512, E=512, H=8, DH=64
// Pipeline: f32->f16 cast, W transpose+cast, fused QKV GEMM (double-buffered
// LDS staging, XCD-chunked block swizzle, packed fragment-order epilogue),
// flash attention (LDS double-buffered K/V in fragment order; mask folded as
// additive bias into MFMA C-init; swapped-operand QK^T, lane-local softmax).
// Workspace:
//   xh  [8192][512] f16   @ 0        (8 MB)
//   wT  [3][512][512] f16 @ 8388608  (1.5 MB)  wT[z][n][k] = W_z[k][n]
//   Qh  @ 9961472  (8 MB)  per head 32 tiles x 8KB: [s(64)][d(64)] f16 linear
//   Kpk @ 18350080 (8 MB)  per head 32 tiles x 8KB, fragment order:
//        byte ((kt*2+ks)*64+lane)*16 = K[key=kt*16+(lane&15)][d=ks*32+(lane>>4)*8 +0..7]
//   Vpk @ 26738688 (8 MB)  per head 32 tiles x 8KB, fragment order:
//        byte ((ks*2+dp)*64+lane)*16 = V[d=(dp*2+i)*16+(lane&15)][key=ks*16+(lane>>4)*4 +0..3], i=0,1

typedef _Float16 f16x4 __attribute__((ext_vector_type(4)));
typedef _Float16 f16x8 __attribute__((ext_vector_type(8)));
typedef float f32x4 __attribute__((ext_vector_type(4)));

#define MFMA16(a, b, c) __builtin_amdgcn_mfma_f32_16x16x16f16((a), (b), (c), 0, 0, 0)
#define MFMA32(a, b, c) __builtin_amdgcn_mfma_f32_16x16x32_f16((a), (b), (c), 0, 0, 0)
#define GLDS16(g, l)                                                                     \
    __builtin_amdgcn_global_load_lds((const __attribute__((address_space(1))) void*)(g), \
                                     (__attribute__((address_space(3))) void*)(l), 16, 0, 0)

constexpr int Bn = 4, Sn = 2048, Fn = 512, En = 512, Hn = 8, DHn = 64;

__global__ void cvt_f32_to_f16(const float* __restrict__ in, _Float16* __restrict__ out, int n4) {
    int i = blockIdx.x * blockDim.x + threadIdx.x;
    int stride = gridDim.x * blockDim.x;
    for (; i < n4; i += stride) {
        float4 v = reinterpret_cast<const float4*>(in)[i];
        f16x4 o = { (_Float16)v.x, (_Float16)v.y, (_Float16)v.z, (_Float16)v.w };
        reinterpret_cast<f16x4*>(out)[i] = o;
    }
}

// wT[z][n][k] = W_z[k][n]
__global__ void cvt_wT(const float* __restrict__ Wq, const float* __restrict__ Wk,
                       const float* __restrict__ Wv, _Float16* __restrict__ out) {
    const int z = blockIdx.z;
    const float* W = (z == 0) ? Wq : ((z == 1) ? Wk : Wv);
    _Float16* o = out + (size_t)z * Fn * En;
    __shared__ float tile[16][17];
    int n = blockIdx.x * 16 + threadIdx.x;
    int k = blockIdx.y * 16 + threadIdx.y;
    tile[threadIdx.y][threadIdx.x] = W[k * En + n];
    __syncthreads();
    int n2 = blockIdx.x * 16 + threadIdx.y;
    int k2 = blockIdx.y * 16 + threadIdx.x;
    o[(size_t)n2 * Fn + k2] = (_Float16)tile[threadIdx.x][threadIdx.y];
}

// Fused QKV GEMM: 128x64 tiles, BK=64, DOUBLE-BUFFERED global_load_lds staging
// (stage t+1 under compute t -> no exposed latency), XCD-chunked swizzle so the
// 24 blocks sharing an A-tile run on one XCD. grid 1536 1-D, 3 blocks/CU.
__global__ __launch_bounds__(256, 3) void qkv_gemm(
    const _Float16* __restrict__ xh, const _Float16* __restrict__ wT,
    const float* __restrict__ bq, const float* __restrict__ bk, const float* __restrict__ bv,
    char* __restrict__ Qh, char* __restrict__ Kpk, char* __restrict__ Vpk) {
    // hwbid = (x%8) + 8*((x/8)*24 + (z*8+y))  ->  invert:
    const int hwbid = blockIdx.x;
    const int t2 = hwbid >> 3;
    const int x = (t2 / 24) * 8 + (hwbid & 7);
    const int r = t2 % 24;
    const int z = r >> 3, y = r & 7;

    const _Float16* Wz = wT + (size_t)z * Fn * En;
    const float* bias = (z == 0) ? bq : ((z == 1) ? bk : bv);

    const int tid = threadIdx.x;
    const int wave = tid >> 6, lane = tid & 63;
    const int lr = lane & 15, hi = lane >> 4;
    const int wr = wave >> 1, wn = wave & 1;
    const int m0 = x * 128;
    const int n0 = y * 64;

    __shared__ __align__(16) char smem[49152];  // 2 x (A 16KB | B 8KB)

    f32x4 acc[4][2] = {};
    const int inrow = (tid & 7) * 16;
    const int rowb = tid >> 3;
    const char* xg = (const char*)xh;
    const char* wg = (const char*)Wz;

    auto stage = [&](int t, char* dst) {
        const int k0b = t * 128;
#pragma unroll
        for (int it = 0; it < 4; ++it) {
            const int row = rowb + it * 32;
            const int sc = inrow ^ ((row & 7) << 4);
            GLDS16(xg + (size_t)(m0 + row) * 1024 + k0b + sc, dst + it * 4096 + tid * 16);
            if (it < 2)
                GLDS16(wg + (size_t)(n0 + row) * 1024 + k0b + sc, dst + 16384 + it * 4096 + tid * 16);
        }
    };

    stage(0, smem);
    asm volatile("s_waitcnt vmcnt(0)" ::: "memory");  // tile 0 landed before first compute
    __syncthreads();

    for (int tp = 0; tp < 4; ++tp) {
#pragma unroll
        for (int u = 0; u < 2; ++u) {
            const int t = tp * 2 + u;
            char* cur = smem + u * 24576;
            char* nxt = smem + (u ^ 1) * 24576;
            stage((t + 1) & 7, nxt);  // t=7 wraps to 0: harmless, branch-free

            char* As = cur;
            char* Bs = cur + 16384;
#pragma unroll
            for (int ks = 0; ks < 2; ++ks) {
                const int kb = (ks * 64 + hi * 16) ^ ((lr & 7) << 4);
                f16x8 af[4], bf[2];
#pragma unroll
                for (int mt = 0; mt < 4; ++mt)
                    af[mt] = *reinterpret_cast<const f16x8*>(As + (wr * 64 + mt * 16 + lr) * 128 + kb);
#pragma unroll
                for (int nt = 0; nt < 2; ++nt)
                    bf[nt] = *reinterpret_cast<const f16x8*>(Bs + (wn * 32 + nt * 16 + lr) * 128 + kb);
#pragma unroll
                for (int mt = 0; mt < 4; ++mt)
#pragma unroll
                    for (int nt = 0; nt < 2; ++nt)
                        acc[mt][nt] = MFMA32(af[mt], bf[nt], acc[mt][nt]);
            }
            asm volatile("s_waitcnt vmcnt(0)" ::: "memory");
            __syncthreads();
        }
    }

    // epilogue: acc(+bias)->f16 swizzled LDS tile [128 s][64 c], then packed stores
    {
        const int cb = wn * 32 + lr;
#pragma unroll
        for (int mt = 0; mt < 4; ++mt) {
            const int sb = wr * 64 + mt * 16 + hi * 4;
#pragma unroll
            for (int nt = 0; nt < 2; ++nt) {
                const int c = cb + nt * 16;
                const float bz = bias[n0 + c];
#pragma unroll
                for (int r2 = 0; r2 < 4; ++r2) {
                    const int s = sb + r2;
                    *reinterpret_cast<_Float16*>(smem + s * 128 + ((c * 2) ^ ((s & 7) << 4))) =
                        (_Float16)(acc[mt][nt][r2] + bz);
                }
            }
        }
    }
    __syncthreads();

    const int bb = m0 >> 11;
    const int bh = bb * 8 + y;
    const int kt0 = (m0 & 2047) >> 6;
    char* outz = (z == 0) ? Qh : ((z == 1) ? Kpk : Vpk);
    char* hb = outz + (size_t)bh * 262144 + (size_t)kt0 * 8192;
    const char* sm = (const char*)smem;

#pragma unroll
    for (int j = 0; j < 4; ++j) {
        const int g = tid * 16 + j * 4096;
        const int T = g >> 13, g13 = g & 8191;
        f16x8 val;
        if (z == 0) {  // Q: [s][64] linear
            const int s = T * 64 + (g13 >> 7);
            val = *reinterpret_cast<const f16x8*>(sm + s * 128 + ((g13 & 127) ^ ((s & 7) << 4)));
        } else if (z == 1) {  // K fragment order
            const int chunk = g13 >> 10, l2 = (g13 >> 4) & 63;
            const int s = T * 64 + (chunk >> 1) * 16 + (l2 & 15);
            const int db = (chunk & 1) * 64 + (l2 >> 4) * 16;
            val = *reinterpret_cast<const f16x8*>(sm + s * 128 + (db ^ ((s & 7) << 4)));
        } else {  // V fragment order (transpose via scalar reads)
            const int chunk = g13 >> 10, l2 = (g13 >> 4) & 63;
            const int ks = chunk >> 1, dp = chunk & 1;
            const int lr2 = l2 & 15, hi2 = l2 >> 4;
#pragma unroll
            for (int i = 0; i < 8; ++i) {
                const int d = (dp * 2 + (i >> 2)) * 16 + lr2;
                const int s = T * 64 + ks * 16 + hi2 * 4 + (i & 3);
                val[i] = *reinterpret_cast<const _Float16*>(sm + s * 128 + ((d * 2) ^ ((s & 7) << 4)));
            }
        }
        *reinterpret_cast<f16x8*>(hb + g) = val;
    }
}

// Flash attention. grid 1024 (bid%32 = head -> XCD L2 locality), 4 waves x 16 q.
// K/V double-buffered in LDS in fragment order (lane-linear ds_read_b128, zero
// conflicts / zero addr-VALU); mask bias staged in LDS, folded into MFMA C-init.
__global__ __launch_bounds__(256, 4) void attn(
    const _Float16* __restrict__ Qh, const char* __restrict__ Kpk,
    const char* __restrict__ Vpk, const int* __restrict__ mask,
    const float* __restrict__ etype, float* __restrict__ out) {
    const int bid = blockIdx.x;
    const int bh = bid & 31, qb = bid >> 5;
    const int b = bh >> 3, h = bh & 7;
    const int tid = threadIdx.x;
    const int wave = tid >> 6, lane = tid & 63;
    const int lr = lane & 15, hi = lane >> 4;
    const int q0 = qb * 64 + wave * 16;

    const _Float16* Qb = Qh + (size_t)bh * Sn * DHn;
    const char* Kb = Kpk + (size_t)bh * 262144;
    const char* Vg = Vpk + (size_t)bh * 262144;
    const int* mb = mask + b * Sn;

    __shared__ __align__(16) char lds[40960];  // [2][16KB] K|V double buffer; 8KB bias

    // stage mask ints (converted to f32 bias in place below) + tile 0 K/V
    {
        const char* ms = (const char*)(mask + b * Sn);
        GLDS16(ms + tid * 16, lds + 32768 + tid * 16);
        GLDS16(ms + tid * 16 + 4096, lds + 32768 + tid * 16 + 4096);
        GLDS16(Kb + tid * 16, lds + tid * 16);
        GLDS16(Kb + tid * 16 + 4096, lds + tid * 16 + 4096);
        GLDS16(Vg + tid * 16, lds + 8192 + tid * 16);
        GLDS16(Vg + tid * 16 + 4096, lds + 8192 + tid * 16 + 4096);
    }

    // Q fragment: col = l&15 = q-row, k = ks*32 + hi*8 + e; add etype, prescale
    constexpr float CSC = 0.18033688011112042f;  // 0.125 * log2(e)
    f16x8 qf[2];
#pragma unroll
    for (int ks = 0; ks < 2; ++ks) {
        const f16x8 qh = *reinterpret_cast<const f16x8*>(Qb + (q0 + lr) * DHn + ks * 32 + hi * 8);
        const float* ep = etype + ((size_t)(b * Sn) + q0 + lr) * En + h * DHn + ks * 32 + hi * 8;
        const f32x4 e0 = *reinterpret_cast<const f32x4*>(ep);
        const f32x4 e1 = *reinterpret_cast<const f32x4*>(ep + 4);
        f16x8 q;
#pragma unroll
        for (int j = 0; j < 4; ++j) q[j] = (_Float16)(((float)qh[j] + e0[j]) * CSC);
#pragma unroll
        for (int j = 0; j < 4; ++j) q[4 + j] = (_Float16)(((float)qh[4 + j] + e1[j]) * CSC);
        qf[ks] = q;
    }

    f32x4 oaccT[4] = {};  // [dt]: row = d-local (hi*4+r), col = q-row (l&15)
    f32x4 osum = {};
    float mrun = -3e38f;
    const f16x4 onev = {(_Float16)1.f, (_Float16)1.f, (_Float16)1.f, (_Float16)1.f};

    asm volatile("s_waitcnt vmcnt(0)" ::: "memory");
    __syncthreads();

    // convert mask ints -> f32 bias in place (0 / -1e30)
    {
        int4 a = *reinterpret_cast<const int4*>(lds + 32768 + tid * 16);
        int4 c = *reinterpret_cast<const int4*>(lds + 32768 + tid * 16 + 4096);
        __syncthreads();
        f32x4 fa = {a.x ? 0.f : -1e30f, a.y ? 0.f : -1e30f, a.z ? 0.f : -1e30f, a.w ? 0.f : -1e30f};
        f32x4 fc = {c.x ? 0.f : -1e30f, c.y ? 0.f : -1e30f, c.z ? 0.f : -1e30f, c.w ? 0.f : -1e30f};
        *reinterpret_cast<f32x4*>(lds + 32768 + tid * 16) = fa;
        *reinterpret_cast<f32x4*>(lds + 32768 + tid * 16 + 4096) = fc;
        __syncthreads();
    }

    const char* kvr = lds + lane * 16;       // fragment read base (per-lane)
    const char* pmb = lds + 32768 + hi * 16; // bias read base (broadcast in 16-group)

    for (int tp = 0; tp < 16; ++tp) {
        const int tb = tp * 512;  // byte offset of this tile-pair's bias (128 keys * 4B)
#pragma unroll
        for (int u = 0; u < 2; ++u) {
            const int t = tp * 2 + u;
            // stage next tile into the other buffer
            const size_t nto = (size_t)((t + 1) & 31) * 8192;
            char* nb = lds + (u ^ 1) * 16384;
            GLDS16(Kb + nto + tid * 16, nb + tid * 16);
            GLDS16(Kb + nto + tid * 16 + 4096, nb + tid * 16 + 4096);
            GLDS16(Vg + nto + tid * 16, nb + 8192 + tid * 16);
            GLDS16(Vg + nto + tid * 16 + 4096, nb + 8192 + tid * 16 + 4096);

            // S^T accumulator initialized from mask bias: key = t*64 + kt*16 + hi*4 + r
            f32x4 scT[4];
#pragma unroll
            for (int kt = 0; kt < 4; ++kt)
                scT[kt] = *reinterpret_cast<const f32x4*>(pmb + tb + u * 256 + kt * 64);

            const char* cb = kvr + u * 16384;
#pragma unroll
            for (int ks = 0; ks < 2; ++ks)
#pragma unroll
                for (int kt = 0; kt < 4; ++kt) {
                    const f16x8 kf = *reinterpret_cast<const f16x8*>(cb + (kt * 2 + ks) * 1024);
                    scT[kt] = MFMA32(kf, qf[ks], scT[kt]);
                }

            // row max: 15 lane-local fmax + 2 shuffles
            float mx = fmaxf(fmaxf(scT[0][0], scT[0][1]), fmaxf(scT[0][2], scT[0][3]));
            mx = fmaxf(mx, fmaxf(fmaxf(scT[1][0], scT[1][1]), fmaxf(scT[1][2], scT[1][3])));
            mx = fmaxf(mx, fmaxf(fmaxf(scT[2][0], scT[2][1]), fmaxf(scT[2][2], scT[2][3])));
            mx = fmaxf(mx, fmaxf(fmaxf(scT[3][0], scT[3][1]), fmaxf(scT[3][2], scT[3][3])));
            mx = fmaxf(mx, __shfl_xor(mx, 16));
            mx = fmaxf(mx, __shfl_xor(mx, 32));

            // defer-max (THR=8)
            if (!__all(mx <= mrun + 8.0f)) {
                const float mnew = fmaxf(mrun, mx);
                const float al = exp2f(mrun - mnew);
                mrun = mnew;
#pragma unroll
                for (int dt = 0; dt < 4; ++dt) oaccT[dt] *= al;
                osum *= al;
            }

            // P = exp2(S - m) -> f16 (register-local)
            f16x4 pa[4];
#pragma unroll
            for (int kt = 0; kt < 4; ++kt) {
                f16x4 p;
#pragma unroll
                for (int r = 0; r < 4; ++r) p[r] = (_Float16)exp2f(scT[kt][r] - mrun);
                pa[kt] = p;
            }

            // PV: V fragments lane-linear; O^T += V^T.P^T ; ones-row sum on MFMA pipe
#pragma unroll
            for (int ks = 0; ks < 4; ++ks) {
#pragma unroll
                for (int dp = 0; dp < 2; ++dp) {
                    const f16x8 vv = *reinterpret_cast<const f16x8*>(cb + 8192 + (ks * 2 + dp) * 1024);
                    const f16x4 v0 = {vv[0], vv[1], vv[2], vv[3]};
                    const f16x4 v1 = {vv[4], vv[5], vv[6], vv[7]};
                    oaccT[dp * 2] = MFMA16(v0, pa[ks], oaccT[dp * 2]);
                    oaccT[dp * 2 + 1] = MFMA16(v1, pa[ks], oaccT[dp * 2 + 1]);
                }
                osum = MFMA16(onev, pa[ks], osum);
            }

            asm volatile("s_waitcnt vmcnt(0)" ::: "memory");
            __syncthreads();
        }
    }

    // epilogue: query-mask zeroing + 1/sum
    const int srow = q0 + lr;
    const float inv = (mb[srow] != 0) ? 1.0f / osum[0] : 0.0f;
#pragma unroll
    for (int dt = 0; dt < 4; ++dt) {
        f32x4 o = oaccT[dt] * inv;
        *reinterpret_cast<f32x4*>(out + ((size_t)(b * Sn + srow)) * En + h * DHn + dt * 16 + hi * 4) = o;
    }
}

extern "C" void kernel_launch(void* const* d_in, const int* in_sizes, int n_in,
                              void* d_out, int out_size, void* d_ws, size_t ws_size,
                              hipStream_t stream) {
    const float* x = (const float*)d_in[0];
    const float* etype = (const float*)d_in[1];
    const int* mask = (const int*)d_in[2];
    const float* Wq = (const float*)d_in[3];
    const float* bq = (const float*)d_in[4];
    const float* Wk = (const float*)d_in[5];
    const float* bk = (const float*)d_in[6];
    const float* Wv = (const float*)d_in[7];
    const float* bv = (const float*)d_in[8];
    float* out = (float*)d_out;

    char* ws = (char*)d_ws;
    _Float16* xh = (_Float16*)(ws + 0);
    _Float16* wT = (_Float16*)(ws + 8388608);
    char* Qh = ws + 9961472;
    char* Kpk = ws + 18350080;
    char* Vpk = ws + 26738688;

    cvt_f32_to_f16<<<2048, 256, 0, stream>>>(x, xh, (Bn * Sn * Fn) / 4);
    cvt_wT<<<dim3(32, 32, 3), dim3(16, 16), 0, stream>>>(Wq, Wk, Wv, wT);
    qkv_gemm<<<1536, 256, 0, stream>>>(xh, wT, bq, bk, bv, Qh, Kpk, Vpk);
    attn<<<1024, 256, 0, stream>>>((const _Float16*)Qh, Kpk, Vpk, mask, etype, out);
}